// Round 1
// baseline (257.346 us; speedup 1.0000x reference)
//
#include <hip/hip_runtime.h>

#define N_POINTS_  2000000
#define IN_CH      10
#define OUT_CH     32
#define NUM_PILLARS 30000
#define BN_EPS     1e-3f

#define BP 32        // points per block (kernel 1)
#define BLOCK 256

// ---------------- kernel 0: zero pillar-max buffer ----------------
__global__ void kzero(unsigned int* __restrict__ p, int n) {
    int i = blockIdx.x * blockDim.x + threadIdx.x;
    if (i < n) p[i] = 0u;
}

// ---------------- kernel 1: linear + BN + ReLU + scatter-max ----------------
__global__ __launch_bounds__(BLOCK) void k_fused(
    const float* __restrict__ in,      // [N,10]
    const int*   __restrict__ inv,     // [N]
    const float* __restrict__ W,       // [32,10]
    const float* __restrict__ gamma,
    const float* __restrict__ beta,
    const float* __restrict__ mean,
    const float* __restrict__ var,
    float*        __restrict__ out,    // [N,64], we fill cols 0..31
    unsigned int* __restrict__ xmax,   // [NUM_PILLARS,32] as uint bits
    int n)
{
    __shared__ float s_scale[OUT_CH];
    __shared__ float s_b[OUT_CH];
    __shared__ float s_Wf[OUT_CH * IN_CH];   // BN-folded weights
    __shared__ float s_in[BP * IN_CH];
    __shared__ float s_x[BP][OUT_CH + 1];    // +1 pad: conflict-free write
    __shared__ int   s_pid[BP];

    const int t = threadIdx.x;
    const int base = blockIdx.x * BP;

    if (t < OUT_CH) {
        float sc = rsqrtf(var[t] + BN_EPS) * gamma[t];
        s_scale[t] = sc;
        s_b[t] = beta[t] - mean[t] * sc;
    }
    __syncthreads();
    for (int i = t; i < OUT_CH * IN_CH; i += BLOCK) {
        int o = i / IN_CH;
        s_Wf[i] = W[i] * s_scale[o];
    }
    for (int i = t; i < BP * IN_CH; i += BLOCK) {
        long g = (long)base * IN_CH + i;
        s_in[i] = (g < (long)n * IN_CH) ? in[g] : 0.f;
    }
    if (t < BP) {
        int p = base + t;
        s_pid[t] = (p < n) ? inv[p] : -1;
    }
    __syncthreads();

    // compute: 8 threads per point, 4 channels each
    const int pl = t >> 3;          // 0..31 local point
    const int cg = t & 7;           // 0..7 channel group
    const int c0 = cg * 4;
    const int point = base + pl;

    float4 acc;
    float* a = &acc.x;
    #pragma unroll
    for (int j = 0; j < 4; ++j) a[j] = s_b[c0 + j];
    #pragma unroll
    for (int i = 0; i < IN_CH; ++i) {
        float xi = s_in[pl * IN_CH + i];
        #pragma unroll
        for (int j = 0; j < 4; ++j)
            a[j] = fmaf(xi, s_Wf[(c0 + j) * IN_CH + i], a[j]);
    }
    #pragma unroll
    for (int j = 0; j < 4; ++j) a[j] = fmaxf(a[j], 0.f);

    bool valid = (point < n);
    if (valid) {
        *reinterpret_cast<float4*>(out + (size_t)point * 64 + c0) = acc;
    }
    #pragma unroll
    for (int j = 0; j < 4; ++j) s_x[pl][c0 + j] = valid ? a[j] : 0.f;
    __syncthreads();

    // segmented max over the block's 32 sorted points; ids sorted -> ~1-2
    // segments per block -> ~48 atomics/block instead of 1024.
    if (t < OUT_CH) {
        const int c = t;
        int curPid = s_pid[0];
        float m = s_x[0][c];
        #pragma unroll 4
        for (int p = 1; p < BP; ++p) {
            int pid = s_pid[p];          // wave-uniform
            if (pid != curPid) {         // wave-uniform branch
                if (curPid >= 0)
                    atomicMax(&xmax[curPid * OUT_CH + c], __float_as_uint(m));
                curPid = pid;
                m = s_x[p][c];
            } else {
                m = fmaxf(m, s_x[p][c]);
            }
        }
        if (curPid >= 0)
            atomicMax(&xmax[curPid * OUT_CH + c], __float_as_uint(m));
    }
}

// ---------------- kernel 2: gather pillar max back per point ----------------
__global__ __launch_bounds__(BLOCK) void k_gather(
    const int*   __restrict__ inv,
    const float* __restrict__ xmax,    // reinterpret uint bits as float (>=0)
    float*       __restrict__ out,     // cols 32..63
    int n)
{
    int idx = blockIdx.x * blockDim.x + threadIdx.x;
    int point = idx >> 3;
    int cg = idx & 7;
    if (point < n) {
        int pid = inv[point];
        float4 v = *reinterpret_cast<const float4*>(xmax + (size_t)pid * OUT_CH + cg * 4);
        *reinterpret_cast<float4*>(out + (size_t)point * 64 + 32 + cg * 4) = v;
    }
}

extern "C" void kernel_launch(void* const* d_in, const int* in_sizes, int n_in,
                              void* d_out, int out_size, void* d_ws, size_t ws_size,
                              hipStream_t stream) {
    const float* in    = (const float*)d_in[0];
    const int*   inv   = (const int*)d_in[1];
    // d_in[2] = num_out_inds scalar (30000), known statically
    const float* W     = (const float*)d_in[3];
    const float* gamma = (const float*)d_in[4];
    const float* beta  = (const float*)d_in[5];
    const float* mean  = (const float*)d_in[6];
    const float* var   = (const float*)d_in[7];
    float* out = (float*)d_out;
    unsigned int* xmax = (unsigned int*)d_ws;   // NUM_PILLARS*OUT_CH uints

    const int n = in_sizes[1];                  // N points

    const int nmax = NUM_PILLARS * OUT_CH;
    kzero<<<(nmax + BLOCK - 1) / BLOCK, BLOCK, 0, stream>>>(xmax, nmax);

    const int nblk1 = (n + BP - 1) / BP;
    k_fused<<<nblk1, BLOCK, 0, stream>>>(in, inv, W, gamma, beta, mean, var,
                                         out, xmax, n);

    const long tot2 = (long)n * 8;              // one thread per (point, 4-ch group)
    const int nblk2 = (int)((tot2 + BLOCK - 1) / BLOCK);
    k_gather<<<nblk2, BLOCK, 0, stream>>>(inv, (const float*)xmax, out, n);
}

// Round 3
// 210.612 us; speedup vs baseline: 1.2219x; 1.2219x over previous
//
#include <hip/hip_runtime.h>

#define IN_CH       10
#define OUT_CH      32
#define NUM_PILLARS 30000
#define BN_EPS      1e-3f

#define BLOCK 256
#define PPT   8              // consecutive points per thread
#define TILE  256            // (BLOCK/8)*PPT points per block
#define GP    4              // points per thread in gather

typedef float fv4 __attribute__((ext_vector_type(4)));

// ---------------- kernel 0: zero pillar-max buffer ----------------
__global__ void kzero(unsigned int* __restrict__ p, int n) {
    int i = blockIdx.x * blockDim.x + threadIdx.x;
    if (i < n) p[i] = 0u;
}

// ---------------- kernel 1: linear + BN + ReLU + scatter-max ----------------
__global__ __launch_bounds__(BLOCK) void k_fused(
    const float* __restrict__ in,      // [N,10]
    const int*   __restrict__ inv,     // [N] sorted pillar ids
    const float* __restrict__ W,       // [32,10]
    const float* __restrict__ gamma,
    const float* __restrict__ beta,
    const float* __restrict__ mean,
    const float* __restrict__ var,
    float*        __restrict__ out,    // [N,64], cols 0..31
    unsigned int* __restrict__ xmax,   // [NUM_PILLARS,32] float bits
    int n)
{
    __shared__ float s_sc[OUT_CH], s_b[OUT_CH];
    __shared__ float s_Wf[OUT_CH * IN_CH];        // BN-folded weights
    __shared__ float s_in[TILE][IN_CH + 1];       // +1 pad
    __shared__ int   s_pid[TILE];

    const int t = threadIdx.x;
    const int base = blockIdx.x * TILE;

    if (t < OUT_CH) {
        float sc = rsqrtf(var[t] + BN_EPS) * gamma[t];
        s_sc[t] = sc;
        s_b[t]  = beta[t] - mean[t] * sc;
    }
    __syncthreads();
    for (int i = t; i < OUT_CH * IN_CH; i += BLOCK)
        s_Wf[i] = W[i] * s_sc[i / IN_CH];
    {
        const long lim = (long)n * IN_CH;
        for (int i = t; i < TILE * IN_CH; i += BLOCK) {
            long g = (long)base * IN_CH + i;
            s_in[i / IN_CH][i % IN_CH] = (g < lim) ? in[g] : 0.f;
        }
        int p = base + t;                          // TILE == BLOCK
        s_pid[t] = (p < n) ? inv[p] : -1;
    }
    __syncthreads();

    const int strip = t >> 3;                      // 0..31 (8 per wave)
    const int c0 = (t & 7) * 4;                    // channel group

    // hoist folded weights + bias into registers (fully static indexing)
    float w0[IN_CH], w1[IN_CH], w2[IN_CH], w3[IN_CH];
    #pragma unroll
    for (int i = 0; i < IN_CH; ++i) {
        w0[i] = s_Wf[(c0 + 0) * IN_CH + i];
        w1[i] = s_Wf[(c0 + 1) * IN_CH + i];
        w2[i] = s_Wf[(c0 + 2) * IN_CH + i];
        w3[i] = s_Wf[(c0 + 3) * IN_CH + i];
    }
    const float b0 = s_b[c0], b1 = s_b[c0 + 1], b2 = s_b[c0 + 2], b3 = s_b[c0 + 3];

    int curPid = -1;
    float m0 = 0.f, m1 = 0.f, m2 = 0.f, m3 = 0.f;

    #pragma unroll
    for (int s = 0; s < PPT; ++s) {
        const int pl = strip * PPT + s;            // consecutive points per thread
        const int point = base + pl;
        const int pid = s_pid[pl];

        float a0 = b0, a1 = b1, a2 = b2, a3 = b3;
        #pragma unroll
        for (int i = 0; i < IN_CH; ++i) {
            const float xi = s_in[pl][i];
            a0 = fmaf(xi, w0[i], a0);
            a1 = fmaf(xi, w1[i], a1);
            a2 = fmaf(xi, w2[i], a2);
            a3 = fmaf(xi, w3[i], a3);
        }
        a0 = fmaxf(a0, 0.f); a1 = fmaxf(a1, 0.f);
        a2 = fmaxf(a2, 0.f); a3 = fmaxf(a3, 0.f);

        if (point < n) {
            fv4 v = {a0, a1, a2, a3};
            __builtin_nontemporal_store(v,
                reinterpret_cast<fv4*>(out + (size_t)point * 64 + c0));
        }

        if (pid != curPid) {                       // strip-uniform branch
            if (curPid >= 0) {
                unsigned int* q = xmax + (size_t)curPid * OUT_CH + c0;
                atomicMax(q + 0, __float_as_uint(m0));
                atomicMax(q + 1, __float_as_uint(m1));
                atomicMax(q + 2, __float_as_uint(m2));
                atomicMax(q + 3, __float_as_uint(m3));
            }
            curPid = pid;
            m0 = a0; m1 = a1; m2 = a2; m3 = a3;
        } else {
            m0 = fmaxf(m0, a0); m1 = fmaxf(m1, a1);
            m2 = fmaxf(m2, a2); m3 = fmaxf(m3, a3);
        }
    }
    if (curPid >= 0) {
        unsigned int* q = xmax + (size_t)curPid * OUT_CH + c0;
        atomicMax(q + 0, __float_as_uint(m0));
        atomicMax(q + 1, __float_as_uint(m1));
        atomicMax(q + 2, __float_as_uint(m2));
        atomicMax(q + 3, __float_as_uint(m3));
    }
}

// ---------------- kernel 2: gather pillar max back per point ----------------
__global__ __launch_bounds__(BLOCK) void k_gather(
    const int*   __restrict__ inv,
    const float* __restrict__ xmaxf,   // float view of xmax bits (>=0)
    float*       __restrict__ out,     // cols 32..63
    int n)
{
    const int idx = blockIdx.x * BLOCK + threadIdx.x;
    const int c0 = (idx & 7) * 4;
    const int p0 = (idx >> 3) * GP;
    #pragma unroll
    for (int s = 0; s < GP; ++s) {
        const int p = p0 + s;
        if (p < n) {
            const int pid = inv[p];
            fv4 v = *reinterpret_cast<const fv4*>(
                xmaxf + (size_t)pid * OUT_CH + c0);
            __builtin_nontemporal_store(v,
                reinterpret_cast<fv4*>(out + (size_t)p * 64 + 32 + c0));
        }
    }
}

extern "C" void kernel_launch(void* const* d_in, const int* in_sizes, int n_in,
                              void* d_out, int out_size, void* d_ws, size_t ws_size,
                              hipStream_t stream) {
    const float* in    = (const float*)d_in[0];
    const int*   inv   = (const int*)d_in[1];
    // d_in[2] = num_out_inds scalar (30000), known statically
    const float* W     = (const float*)d_in[3];
    const float* gamma = (const float*)d_in[4];
    const float* beta  = (const float*)d_in[5];
    const float* mean  = (const float*)d_in[6];
    const float* var   = (const float*)d_in[7];
    float* out = (float*)d_out;
    unsigned int* xmax = (unsigned int*)d_ws;   // NUM_PILLARS*OUT_CH uints

    const int n = in_sizes[1];

    const int nmax = NUM_PILLARS * OUT_CH;
    kzero<<<(nmax + BLOCK - 1) / BLOCK, BLOCK, 0, stream>>>(xmax, nmax);

    const int nblk1 = (n + TILE - 1) / TILE;
    k_fused<<<nblk1, BLOCK, 0, stream>>>(in, inv, W, gamma, beta, mean, var,
                                         out, xmax, n);

    const long tg = ((long)((n + GP - 1) / GP)) * 8;
    const int nblk2 = (int)((tg + BLOCK - 1) / BLOCK);
    k_gather<<<nblk2, BLOCK, 0, stream>>>(inv, (const float*)xmax, out, n);
}

// Round 4
// 183.440 us; speedup vs baseline: 1.4029x; 1.1481x over previous
//
#include <hip/hip_runtime.h>

#define IN_CH       10
#define OUT_CH      32
#define NUM_PILLARS 30000
#define BN_EPS      1e-3f

#define BLOCK 256
#define TILEA 512            // points per block in k_scatter (PPT=16)
#define PPTA  16
#define TILEB 256            // points per block in k_write

typedef float fv4 __attribute__((ext_vector_type(4)));
typedef float fv2 __attribute__((ext_vector_type(2)));

// ---------------- kernel 0: zero pillar-max buffer ----------------
__global__ void kzero(fv4* __restrict__ p, int n4) {
    int i = blockIdx.x * blockDim.x + threadIdx.x;
    if (i < n4) { fv4 z = {0.f, 0.f, 0.f, 0.f}; p[i] = z; }
}

// ---------------- kernel 1: linear+BN+ReLU -> segment-max atomics only ----
__global__ __launch_bounds__(BLOCK) void k_scatter(
    const float* __restrict__ in,      // [N,10]
    const int*   __restrict__ inv,     // [N] sorted
    const float* __restrict__ W,       // [32,10]
    const float* __restrict__ gamma,
    const float* __restrict__ beta,
    const float* __restrict__ mean,
    const float* __restrict__ var,
    unsigned int* __restrict__ xmax,   // [NUM_PILLARS,32] float bits
    int n)
{
    __shared__ float s_sc[OUT_CH], s_b[OUT_CH];
    __shared__ float s_Wf[OUT_CH * IN_CH];
    __shared__ float s_in[TILEA][12];          // 10 used, 12 for 16B-aligned rows
    __shared__ int   s_pid[TILEA];

    const int t = threadIdx.x;
    const long base = (long)blockIdx.x * TILEA;

    if (t < OUT_CH) {
        float sc = rsqrtf(var[t] + BN_EPS) * gamma[t];
        s_sc[t] = sc;
        s_b[t]  = beta[t] - mean[t] * sc;
    }
    __syncthreads();
    for (int i = t; i < OUT_CH * IN_CH; i += BLOCK)
        s_Wf[i] = W[i] * s_sc[i / IN_CH];

    const long lim2 = (long)n * IN_CH;
    #pragma unroll
    for (int k = 0; k < (TILEA * IN_CH) / (BLOCK * 2); ++k) {   // 10 iters
        const int f = (t + k * BLOCK) * 2;
        const long g = base * IN_CH + f;
        fv2 v = {0.f, 0.f};
        if (g < lim2) v = *reinterpret_cast<const fv2*>(in + g);
        const int r = f / IN_CH, c = f - r * IN_CH;             // c even, <=8
        s_in[r][c] = v.x; s_in[r][c + 1] = v.y;
    }
    #pragma unroll
    for (int k = 0; k < TILEA / BLOCK; ++k) {
        const long p = base + t + k * BLOCK;
        s_pid[t + k * BLOCK] = (p < n) ? inv[p] : -1;
    }
    __syncthreads();

    const int strip = t >> 3;                  // 0..31
    const int c0 = (t & 7) * 4;

    float w0[IN_CH], w1[IN_CH], w2[IN_CH], w3[IN_CH];
    #pragma unroll
    for (int i = 0; i < IN_CH; ++i) {
        w0[i] = s_Wf[(c0 + 0) * IN_CH + i];
        w1[i] = s_Wf[(c0 + 1) * IN_CH + i];
        w2[i] = s_Wf[(c0 + 2) * IN_CH + i];
        w3[i] = s_Wf[(c0 + 3) * IN_CH + i];
    }
    const float b0 = s_b[c0], b1 = s_b[c0 + 1], b2 = s_b[c0 + 2], b3 = s_b[c0 + 3];

    int curPid = -1;
    float m0 = 0.f, m1 = 0.f, m2 = 0.f, m3 = 0.f;

    #pragma unroll
    for (int s = 0; s < PPTA; ++s) {
        const int pl = strip * PPTA + s;
        const int pid = s_pid[pl];

        const fv4 x0 = *reinterpret_cast<const fv4*>(&s_in[pl][0]);
        const fv4 x1 = *reinterpret_cast<const fv4*>(&s_in[pl][4]);
        const fv2 x2 = *reinterpret_cast<const fv2*>(&s_in[pl][8]);
        const float xi[IN_CH] = {x0[0], x0[1], x0[2], x0[3],
                                 x1[0], x1[1], x1[2], x1[3], x2[0], x2[1]};

        float a0 = b0, a1 = b1, a2 = b2, a3 = b3;
        #pragma unroll
        for (int i = 0; i < IN_CH; ++i) {
            a0 = fmaf(xi[i], w0[i], a0);
            a1 = fmaf(xi[i], w1[i], a1);
            a2 = fmaf(xi[i], w2[i], a2);
            a3 = fmaf(xi[i], w3[i], a3);
        }
        a0 = fmaxf(a0, 0.f); a1 = fmaxf(a1, 0.f);
        a2 = fmaxf(a2, 0.f); a3 = fmaxf(a3, 0.f);

        if (pid != curPid) {
            if (curPid >= 0) {
                unsigned int* q = xmax + (size_t)curPid * OUT_CH + c0;
                atomicMax(q + 0, __float_as_uint(m0));
                atomicMax(q + 1, __float_as_uint(m1));
                atomicMax(q + 2, __float_as_uint(m2));
                atomicMax(q + 3, __float_as_uint(m3));
            }
            curPid = pid;
            m0 = a0; m1 = a1; m2 = a2; m3 = a3;
        } else {
            m0 = fmaxf(m0, a0); m1 = fmaxf(m1, a1);
            m2 = fmaxf(m2, a2); m3 = fmaxf(m3, a3);
        }
    }
    if (curPid >= 0) {
        unsigned int* q = xmax + (size_t)curPid * OUT_CH + c0;
        atomicMax(q + 0, __float_as_uint(m0));
        atomicMax(q + 1, __float_as_uint(m1));
        atomicMax(q + 2, __float_as_uint(m2));
        atomicMax(q + 3, __float_as_uint(m3));
    }
}

// ------- kernel 2: recompute x + gather xmax, write FULL rows contiguously --
__global__ __launch_bounds__(BLOCK) void k_write(
    const float* __restrict__ in,
    const int*   __restrict__ inv,
    const float* __restrict__ W,
    const float* __restrict__ gamma,
    const float* __restrict__ beta,
    const float* __restrict__ mean,
    const float* __restrict__ var,
    const float* __restrict__ xmaxf,   // float view (>=0)
    float*       __restrict__ out,     // [N,64]
    int n)
{
    __shared__ float s_sc[OUT_CH], s_b[OUT_CH];
    __shared__ float s_Wf[OUT_CH * IN_CH];
    __shared__ float s_in[TILEB][12];
    __shared__ int   s_pid[TILEB];

    const int t = threadIdx.x;
    const long base = (long)blockIdx.x * TILEB;

    if (t < OUT_CH) {
        float sc = rsqrtf(var[t] + BN_EPS) * gamma[t];
        s_sc[t] = sc;
        s_b[t]  = beta[t] - mean[t] * sc;
    }
    __syncthreads();
    for (int i = t; i < OUT_CH * IN_CH; i += BLOCK)
        s_Wf[i] = W[i] * s_sc[i / IN_CH];

    const long lim2 = (long)n * IN_CH;
    #pragma unroll
    for (int k = 0; k < (TILEB * IN_CH) / (BLOCK * 2); ++k) {   // 5 iters
        const int f = (t + k * BLOCK) * 2;
        const long g = base * IN_CH + f;
        fv2 v = {0.f, 0.f};
        if (g < lim2) v = *reinterpret_cast<const fv2*>(in + g);
        const int r = f / IN_CH, c = f - r * IN_CH;
        s_in[r][c] = v.x; s_in[r][c + 1] = v.y;
    }
    {
        const long p = base + t;
        s_pid[t] = (p < n) ? inv[p] : 0;
    }
    __syncthreads();

    const int c  = t & 15;                 // slot within 256B row (16 x fv4)
    const int c0 = (c & 7) * 4;            // channel group for either half
    const int pquad = t >> 4;              // 0..15

    float w0[IN_CH], w1[IN_CH], w2[IN_CH], w3[IN_CH];
    #pragma unroll
    for (int i = 0; i < IN_CH; ++i) {
        w0[i] = s_Wf[(c0 + 0) * IN_CH + i];
        w1[i] = s_Wf[(c0 + 1) * IN_CH + i];
        w2[i] = s_Wf[(c0 + 2) * IN_CH + i];
        w3[i] = s_Wf[(c0 + 3) * IN_CH + i];
    }
    const float b0 = s_b[c0], b1 = s_b[c0 + 1], b2 = s_b[c0 + 2], b3 = s_b[c0 + 3];

    #pragma unroll
    for (int s = 0; s < TILEB / 16; ++s) {     // 16 iters, 16 points each
        const int pl = s * 16 + pquad;
        const long point = base + pl;
        fv4 v;
        if (c < 8) {
            const fv4 x0 = *reinterpret_cast<const fv4*>(&s_in[pl][0]);
            const fv4 x1 = *reinterpret_cast<const fv4*>(&s_in[pl][4]);
            const fv2 x2 = *reinterpret_cast<const fv2*>(&s_in[pl][8]);
            const float xi[IN_CH] = {x0[0], x0[1], x0[2], x0[3],
                                     x1[0], x1[1], x1[2], x1[3], x2[0], x2[1]};
            float a0 = b0, a1 = b1, a2 = b2, a3 = b3;
            #pragma unroll
            for (int i = 0; i < IN_CH; ++i) {
                a0 = fmaf(xi[i], w0[i], a0);
                a1 = fmaf(xi[i], w1[i], a1);
                a2 = fmaf(xi[i], w2[i], a2);
                a3 = fmaf(xi[i], w3[i], a3);
            }
            v[0] = fmaxf(a0, 0.f); v[1] = fmaxf(a1, 0.f);
            v[2] = fmaxf(a2, 0.f); v[3] = fmaxf(a3, 0.f);
        } else {
            const int pid = s_pid[pl];
            v = *reinterpret_cast<const fv4*>(xmaxf + (size_t)pid * OUT_CH + c0);
        }
        if (point < n) {
            __builtin_nontemporal_store(v,
                reinterpret_cast<fv4*>(out + (size_t)point * 64 + c * 4));
        }
    }
}

extern "C" void kernel_launch(void* const* d_in, const int* in_sizes, int n_in,
                              void* d_out, int out_size, void* d_ws, size_t ws_size,
                              hipStream_t stream) {
    const float* in    = (const float*)d_in[0];
    const int*   inv   = (const int*)d_in[1];
    // d_in[2] = num_out_inds scalar (30000), known statically
    const float* W     = (const float*)d_in[3];
    const float* gamma = (const float*)d_in[4];
    const float* beta  = (const float*)d_in[5];
    const float* mean  = (const float*)d_in[6];
    const float* var   = (const float*)d_in[7];
    float* out = (float*)d_out;
    unsigned int* xmax = (unsigned int*)d_ws;   // NUM_PILLARS*OUT_CH uints

    const int n = in_sizes[1];

    const int n4 = (NUM_PILLARS * OUT_CH) / 4;
    kzero<<<(n4 + BLOCK - 1) / BLOCK, BLOCK, 0, stream>>>((fv4*)xmax, n4);

    const int nblkA = (int)((n + TILEA - 1) / TILEA);
    k_scatter<<<nblkA, BLOCK, 0, stream>>>(in, inv, W, gamma, beta, mean, var,
                                           xmax, n);

    const int nblkB = (int)((n + TILEB - 1) / TILEB);
    k_write<<<nblkB, BLOCK, 0, stream>>>(in, inv, W, gamma, beta, mean, var,
                                         (const float*)xmax, out, n);
}